// Round 10
// baseline (108.671 us; speedup 1.0000x reference)
//
#include <hip/hip_runtime.h>

#define NELEC 64
#define NDIM 3
#define BPB 4                 // batches per block (1 wave = 1 batch)
#define BLOCK (BPB * NELEC)   // 256 threads
#define REP 5                 // work replicas in ONE dispatch (diagnostic: 5x
                              // amplifies kernel-time deltas and pushes this
                              // dispatch into rocprof's top-5 so we finally
                              // see OUR counters, not fillBuffer's)

#if defined(__has_builtin)
#if __has_builtin(__builtin_amdgcn_rsqf)
#define RSQ(x) __builtin_amdgcn_rsqf(x)
#endif
#endif
#ifndef RSQ
#define RSQ(x) rsqrtf(x)
#endif

#define EPS 1e-37f

__global__ __launch_bounds__(BLOCK) void backflow_kernel(
    const float* __restrict__ pos, const float* __restrict__ w,
    float* __restrict__ out, int B, int grid0)
{
    const int t = threadIdx.x;
    const int i = t & 63;                      // electron index
    // replica fold: blocks [0,grid0) , [grid0,2*grid0) ... all do identical
    // work and write identical values (benign overlap, deterministic)
    const int blk = blockIdx.x % grid0;
    const int b = blk * BPB + (t >> 6);        // wave id == batch
    if (b >= B) return;                        // no barriers below -> safe

    const int bu = __builtin_amdgcn_readfirstlane(b);
    const float* __restrict__ rbase = pos + bu * (NELEC * NDIM);

    // own electron: per-lane 12B load, wave covers 768 contiguous B (coalesced)
    const float* p = rbase + i * NDIM;
    const float rx = p[0], ry = p[1], rz = p[2];

    const float wv = w[0];                     // uniform -> s_load

    // 4-way split accumulators: quarter-length fma dependency chains
    float ax0 = 0.f, ay0 = 0.f, az0 = 0.f;
    float ax1 = 0.f, ay1 = 0.f, az1 = 0.f;
    float ax2 = 0.f, ay2 = 0.f, az2 = 0.f;
    float ax3 = 0.f, ay3 = 0.f, az3 = 0.f;

    #pragma unroll 4
    for (int j = 0; j < NELEC; j += 4) {
        // 12 wave-uniform floats -> SGPRs via K$ (s_load_dwordx* streams)
        const float ax_ = rbase[3*j + 0],  ay_ = rbase[3*j + 1],  az_ = rbase[3*j + 2];
        const float bx_ = rbase[3*j + 3],  by_ = rbase[3*j + 4],  bz_ = rbase[3*j + 5];
        const float cx_ = rbase[3*j + 6],  cy_ = rbase[3*j + 7],  cz_ = rbase[3*j + 8];
        const float ex_ = rbase[3*j + 9],  ey_ = rbase[3*j + 10], ez_ = rbase[3*j + 11];

        float dx0 = rx - ax_, dy0 = ry - ay_, dz0 = rz - az_;
        float dx1 = rx - bx_, dy1 = ry - by_, dz1 = rz - bz_;
        float dx2 = rx - cx_, dy2 = ry - cy_, dz2 = rz - cz_;
        float dx3 = rx - ex_, dy3 = ry - ey_, dz3 = rz - ez_;

        // epsilon folded into the fma chain: replaces mul+fmax with pure fma.
        // j==i: d2==EPS -> rsq finite -> finite*0 == 0. j!=i: +1e-37 is
        // invisible against any normal d2 (identical fp32 result).
        float d20 = fmaf(dz0, dz0, fmaf(dy0, dy0, fmaf(dx0, dx0, EPS)));
        float d21 = fmaf(dz1, dz1, fmaf(dy1, dy1, fmaf(dx1, dx1, EPS)));
        float d22 = fmaf(dz2, dz2, fmaf(dy2, dy2, fmaf(dx2, dx2, EPS)));
        float d23 = fmaf(dz3, dz3, fmaf(dy3, dy3, fmaf(dx3, dx3, EPS)));

        float inv0 = RSQ(d20);
        float inv1 = RSQ(d21);
        float inv2 = RSQ(d22);
        float inv3 = RSQ(d23);

        ax0 = fmaf(inv0, dx0, ax0); ay0 = fmaf(inv0, dy0, ay0); az0 = fmaf(inv0, dz0, az0);
        ax1 = fmaf(inv1, dx1, ax1); ay1 = fmaf(inv1, dy1, ay1); az1 = fmaf(inv1, dz1, az1);
        ax2 = fmaf(inv2, dx2, ax2); ay2 = fmaf(inv2, dy2, ay2); az2 = fmaf(inv2, dz2, az2);
        ax3 = fmaf(inv3, dx3, ax3); ay3 = fmaf(inv3, dy3, ay3); az3 = fmaf(inv3, dz3, az3);
    }

    const float axs = (ax0 + ax1) + (ax2 + ax3);
    const float ays = (ay0 + ay1) + (ay2 + ay3);
    const float azs = (az0 + az1) + (az2 + az3);
    float* dst = out + b * (NELEC * NDIM) + i * NDIM;  // 12B/lane, coalesced
    dst[0] = fmaf(wv, axs, rx);
    dst[1] = fmaf(wv, ays, ry);
    dst[2] = fmaf(wv, azs, rz);
}

extern "C" void kernel_launch(void* const* d_in, const int* in_sizes, int n_in,
                              void* d_out, int out_size, void* d_ws, size_t ws_size,
                              hipStream_t stream) {
    const float* pos = (const float*)d_in[0];
    const float* w   = (const float*)d_in[1];
    float* out       = (float*)d_out;
    const int B = in_sizes[0] / (NELEC * NDIM);
    const int grid0 = (B + BPB - 1) / BPB;
    // DIAGNOSTIC: one dispatch, REP x replicated grid (identical work+values).
    backflow_kernel<<<dim3(grid0 * REP), dim3(BLOCK), 0, stream>>>(pos, w, out, B, grid0);
}

// Round 14
// 70.959 us; speedup vs baseline: 1.5315x; 1.5315x over previous
//
#include <hip/hip_runtime.h>

#define NELEC 64
#define NDIM 3
#define BPB 4                 // batches per block (1 wave = 1 batch)
#define BLOCK (BPB * NELEC)   // 256 threads

#if defined(__has_builtin)
#if __has_builtin(__builtin_amdgcn_rsqf)
#define RSQ(x) __builtin_amdgcn_rsqf(x)
#endif
#endif
#ifndef RSQ
#define RSQ(x) rsqrtf(x)
#endif

#define EPS 1e-37f

__global__ __launch_bounds__(BLOCK) void backflow_kernel(
    const float* __restrict__ pos, const float* __restrict__ w,
    float* __restrict__ out, int B)
{
    const int t = threadIdx.x;
    const int i = t & 63;                      // electron index
    const int b = blockIdx.x * BPB + (t >> 6); // wave id == batch
    if (b >= B) return;                        // no barriers below -> safe

    const int bu = __builtin_amdgcn_readfirstlane(b);
    const float* __restrict__ rbase = pos + bu * (NELEC * NDIM);

    // own electron: per-lane 12B load, wave covers 768 contiguous B (coalesced)
    const float* p = rbase + i * NDIM;
    const float rx = p[0], ry = p[1], rz = p[2];

    const float wv = w[0];                     // uniform -> s_load

    // 4-way split accumulators: quarter-length fma dependency chains
    float ax0 = 0.f, ay0 = 0.f, az0 = 0.f;
    float ax1 = 0.f, ay1 = 0.f, az1 = 0.f;
    float ax2 = 0.f, ay2 = 0.f, az2 = 0.f;
    float ax3 = 0.f, ay3 = 0.f, az3 = 0.f;

    // FULL unroll: straight-line 64 pairs lets the compiler hoist the
    // wave-uniform s_load streams (K$) many chunks ahead of use, hiding
    // SMEM latency under VALU+trans issue (the 22% stall seen at unroll 4).
    #pragma unroll
    for (int j = 0; j < NELEC; j += 4) {
        // 12 wave-uniform floats -> SGPRs via K$ (s_load_dwordx* streams)
        const float ax_ = rbase[3*j + 0],  ay_ = rbase[3*j + 1],  az_ = rbase[3*j + 2];
        const float bx_ = rbase[3*j + 3],  by_ = rbase[3*j + 4],  bz_ = rbase[3*j + 5];
        const float cx_ = rbase[3*j + 6],  cy_ = rbase[3*j + 7],  cz_ = rbase[3*j + 8];
        const float ex_ = rbase[3*j + 9],  ey_ = rbase[3*j + 10], ez_ = rbase[3*j + 11];

        float dx0 = rx - ax_, dy0 = ry - ay_, dz0 = rz - az_;
        float dx1 = rx - bx_, dy1 = ry - by_, dz1 = rz - bz_;
        float dx2 = rx - cx_, dy2 = ry - cy_, dz2 = rz - cz_;
        float dx3 = rx - ex_, dy3 = ry - ey_, dz3 = rz - ez_;

        // epsilon folded into the fma chain (no v_max). j==i: d2==EPS ->
        // rsq finite -> finite*0 == 0. j!=i: +1e-37 is invisible against
        // any normal d2 (identical fp32 result).
        float d20 = fmaf(dz0, dz0, fmaf(dy0, dy0, fmaf(dx0, dx0, EPS)));
        float d21 = fmaf(dz1, dz1, fmaf(dy1, dy1, fmaf(dx1, dx1, EPS)));
        float d22 = fmaf(dz2, dz2, fmaf(dy2, dy2, fmaf(dx2, dx2, EPS)));
        float d23 = fmaf(dz3, dz3, fmaf(dy3, dy3, fmaf(dx3, dx3, EPS)));

        float inv0 = RSQ(d20);
        float inv1 = RSQ(d21);
        float inv2 = RSQ(d22);
        float inv3 = RSQ(d23);

        ax0 = fmaf(inv0, dx0, ax0); ay0 = fmaf(inv0, dy0, ay0); az0 = fmaf(inv0, dz0, az0);
        ax1 = fmaf(inv1, dx1, ax1); ay1 = fmaf(inv1, dy1, ay1); az1 = fmaf(inv1, dz1, az1);
        ax2 = fmaf(inv2, dx2, ax2); ay2 = fmaf(inv2, dy2, ay2); az2 = fmaf(inv2, dz2, az2);
        ax3 = fmaf(inv3, dx3, ax3); ay3 = fmaf(inv3, dy3, ay3); az3 = fmaf(inv3, dz3, az3);
    }

    const float axs = (ax0 + ax1) + (ax2 + ax3);
    const float ays = (ay0 + ay1) + (ay2 + ay3);
    const float azs = (az0 + az1) + (az2 + az3);
    float* dst = out + b * (NELEC * NDIM) + i * NDIM;  // 12B/lane, coalesced
    dst[0] = fmaf(wv, axs, rx);
    dst[1] = fmaf(wv, ays, ry);
    dst[2] = fmaf(wv, azs, rz);
}

extern "C" void kernel_launch(void* const* d_in, const int* in_sizes, int n_in,
                              void* d_out, int out_size, void* d_ws, size_t ws_size,
                              hipStream_t stream) {
    const float* pos = (const float*)d_in[0];
    const float* w   = (const float*)d_in[1];
    float* out       = (float*)d_out;
    const int B = in_sizes[0] / (NELEC * NDIM);
    const int grid = (B + BPB - 1) / BPB;
    backflow_kernel<<<dim3(grid), dim3(BLOCK), 0, stream>>>(pos, w, out, B);
}